// Round 11
// baseline (3370.673 us; speedup 1.0000x reference)
//
#include <hip/hip_runtime.h>
#include <stdint.h>

// ModeloNeuralVasicek — two-phase mean-recursion.
// Round 11: layer 2 as MFMA (v_mfma_f32_16x16x32_f16) with W2 pinned in
// AGPRs as B-fragments. R10's compile failure proved VOP3P can't source
// AGPRs; MFMA is the ONLY fast consumer of AGPR-resident weights (ISA §10).
// Structure: wave 0 = mu-MLP, wave 1 = si-MLP (lane l owns j=l, j=l+64);
// waves 2,3 only match barrier counts. A-fragment rows are all copies of h1
// (rows!=0 ignored) => every lane's acc[0] holds h2[16c+(lane&15)] directly,
// no extraction shuffles. One barrier/step (parity-buffered mu/si exchange).
// B layout assumed symmetric to verified A layout: B[k=quad*8+i][n=lane&15].

#define NSTEPS 2520
#define NB 64
#define NT 256
#define NQ 256
#define NMAT 7

typedef uint32_t u32x4 __attribute__((ext_vector_type(4)));
typedef float f32x4 __attribute__((ext_vector_type(4)));

__device__ uint32_t g_done;

__device__ __forceinline__ uint32_t rotl32(uint32_t v, int n) {
  return (v << n) | (v >> (32 - n));
}

// Threefry-2x32, 20 rounds — matches jax._src.prng.threefry2x32 exactly.
__device__ __forceinline__ void tf2x32(uint32_t k0, uint32_t k1,
                                       uint32_t x0, uint32_t x1,
                                       uint32_t& o0, uint32_t& o1) {
  const uint32_t k2 = k0 ^ k1 ^ 0x1BD11BDAu;
  x0 += k0; x1 += k1;
#define R4(a,b,c,d) \
  x0 += x1; x1 = rotl32(x1,(a)); x1 ^= x0; \
  x0 += x1; x1 = rotl32(x1,(b)); x1 ^= x0; \
  x0 += x1; x1 = rotl32(x1,(c)); x1 ^= x0; \
  x0 += x1; x1 = rotl32(x1,(d)); x1 ^= x0;
  R4(13,15,26,6)  x0 += k1; x1 += k2 + 1u;
  R4(17,29,16,24) x0 += k2; x1 += k0 + 2u;
  R4(13,15,26,6)  x0 += k0; x1 += k1 + 3u;
  R4(17,29,16,24) x0 += k1; x1 += k2 + 4u;
  R4(13,15,26,6)  x0 += k2; x1 += k0 + 5u;
#undef R4
  o0 = x0; o1 = x1;
}

// Eigen/XLA generic_fast_tanh_float.
__device__ __forceinline__ float eigen_tanh(float a_x) {
  float x = fminf(fmaxf(a_x, -7.90531110763549805f), 7.90531110763549805f);
  float x2 = x * x;
  float p = __builtin_fmaf(x2, -2.76076847742355e-16f, 2.00018790482477e-13f);
  p = __builtin_fmaf(x2, p, -8.60467152213735e-11f);
  p = __builtin_fmaf(x2, p, 5.12229709037114e-08f);
  p = __builtin_fmaf(x2, p, 1.48572235717979e-05f);
  p = __builtin_fmaf(x2, p, 6.37261928875436e-04f);
  p = __builtin_fmaf(x2, p, 4.89352455891786e-03f);
  p = x * p;
  float q = __builtin_fmaf(x2, 1.19825839466702e-06f, 1.18534705686654e-04f);
  q = __builtin_fmaf(x2, q, 2.26843463243900e-03f);
  q = __builtin_fmaf(x2, q, 4.89352518554385e-03f);
  float rr = p / q;
  return (fabsf(a_x) < 0.0004f) ? a_x : rr;
}

// Eigen/XLA generic_fast_erf_float.
__device__ __forceinline__ float eigen_erf(float a_x) {
  float x = fminf(fmaxf(a_x, -4.0f), 4.0f);
  float x2 = x * x;
  float p = __builtin_fmaf(x2, -2.72614225801306e-10f, 2.77068142495902e-08f);
  p = __builtin_fmaf(x2, p, -2.10102402082508e-06f);
  p = __builtin_fmaf(x2, p, -5.69250639462346e-05f);
  p = __builtin_fmaf(x2, p, -7.34990630326855e-04f);
  p = __builtin_fmaf(x2, p, -2.95459980854025e-03f);
  p = __builtin_fmaf(x2, p, -1.60960333262415e-02f);
  p = x * p;
  float q = __builtin_fmaf(x2, -1.45660718464996e-05f, -2.13374055278905e-04f);
  q = __builtin_fmaf(x2, q, -1.68282697438203e-03f);
  q = __builtin_fmaf(x2, q, -7.37332916720468e-03f);
  q = __builtin_fmaf(x2, q, -1.42647390514189e-02f);
  return p / q;
}

__device__ __forceinline__ float gelu_exact(float x) {
  float t = x / 1.41421356237309515f;
  float e = eigen_erf(t);
  return x * (e + 1.0f) * 0.5f;
}

__device__ __forceinline__ float softplus_jax(float x) {
  return fmaxf(x, 0.0f) + log1pf(expf(-fabsf(x)));
}

// XLA chlo.erf_inv f32 (Giles polynomial).
__device__ __forceinline__ float erfinv_xla(float x) {
  float w = -logf((1.0f - x) * (1.0f + x));
  float p;
  if (w < 5.0f) {
    w = w - 2.5f;
    p = 2.81022636e-08f;
    p = __builtin_fmaf(p, w, 3.43273939e-07f);
    p = __builtin_fmaf(p, w, -3.5233877e-06f);
    p = __builtin_fmaf(p, w, -4.39150654e-06f);
    p = __builtin_fmaf(p, w, 0.00021858087f);
    p = __builtin_fmaf(p, w, -0.00125372503f);
    p = __builtin_fmaf(p, w, -0.00417768164f);
    p = __builtin_fmaf(p, w, 0.246640727f);
    p = __builtin_fmaf(p, w, 1.50140941f);
  } else {
    w = sqrtf(w) - 3.0f;
    p = -0.000200214257f;
    p = __builtin_fmaf(p, w, 0.000100950558f);
    p = __builtin_fmaf(p, w, 0.00134934322f);
    p = __builtin_fmaf(p, w, -0.00367342844f);
    p = __builtin_fmaf(p, w, 0.00573950773f);
    p = __builtin_fmaf(p, w, -0.0076224613f);
    p = __builtin_fmaf(p, w, 0.00943887047f);
    p = __builtin_fmaf(p, w, 1.00167406f);
    p = __builtin_fmaf(p, w, 2.83297682f);
  }
  return p * x;
}

__device__ __forceinline__ float bits_to_normal(uint32_t bits) {
  const float MINVAL = -0.999999940395355224609375f;
  uint32_t fb = (bits >> 9) | 0x3F800000u;
  float f01 = __uint_as_float(fb) - 1.0f;
  float u = f01 * 2.0f + MINVAL;
  u = fmaxf(u, MINVAL);
  return 1.41421356237309515f * erfinv_xla(u);
}

__device__ __forceinline__ uint16_t f32_to_f16bits(float x) {
  _Float16 hv = (_Float16)x;  // RNE
  return __builtin_bit_cast(uint16_t, hv);
}

__device__ __forceinline__ uint32_t pack_f16x2(float lo, float hi) {
  return (uint32_t)f32_to_f16bits(lo) | ((uint32_t)f32_to_f16bits(hi) << 16);
}

#define DTF  0.00396825396825396826f
#define SQDT 0.06299407883487120442f
#define TSTEP (1.0f / 2519.0f)

// ---------------- Phase 1: mean_dW[b][s] — fully parallel ----------------
__global__ __launch_bounds__(256)
void vasicek_phase1_meandw(float* __restrict__ ws) {
  if (blockIdx.x == 0 && threadIdx.x == 0)
    __hip_atomic_store(&g_done, 0u, __ATOMIC_RELAXED, __HIP_MEMORY_SCOPE_AGENT);
  const int tid = threadIdx.x;
  const int lane = tid & 63;
  const int wv = tid >> 6;
  const int wid = blockIdx.x * 4 + wv;          // 0 .. 64*2520-1
  const int b = wid / NSTEPS;
  const int s = wid - b * NSTEPS;

  uint32_t kA, kB;
  tf2x32(0u, 1u, 0u, (uint32_t)s, kA, kB);      // split(key(1))[s]

  float sum = 0.f;
#pragma unroll
  for (int i = 0; i < 4; ++i) {
    uint32_t cnt = (uint32_t)(b * NQ + lane + i * 64);
    uint32_t q0, q1;
    tf2x32(kA, kB, 0u, cnt, q0, q1);
    float dw = bits_to_normal(q0 ^ q1) * SQDT;
    sum += dw;
  }
  sum += __shfl_xor(sum, 32, 64); sum += __shfl_xor(sum, 16, 64);
  sum += __shfl_xor(sum, 8, 64);  sum += __shfl_xor(sum, 4, 64);
  sum += __shfl_xor(sum, 2, 64);  sum += __shfl_xor(sum, 1, 64);
  if (lane == 0) ws[b * NSTEPS + s] = sum * (1.0f / 256.0f);
}

// ---- B-fragment (W2) machinery: 32 AGPR quads per scan thread ------------
// B[k][n] tile (T=k/32, C=n/16): lane (q=lane>>4, n=lane&15), elem i holds
// W2[32T + 8q + i][16C + n]; dword d = elems (2d, 2d+1) packed f16.
#define BDECL(T, C) u32x4 bf_##T##_##C;
#define BINIT(T, C) { \
  const float* wsrc_ = W2src + (32 * (T) + 8 * q) * 128 + 16 * (C) + n; \
  bf_##T##_##C = (u32x4){ \
    pack_f16x2(wsrc_[0],   wsrc_[128]), \
    pack_f16x2(wsrc_[256], wsrc_[384]), \
    pack_f16x2(wsrc_[512], wsrc_[640]), \
    pack_f16x2(wsrc_[768], wsrc_[896])}; \
  asm volatile("" : "+a"(bf_##T##_##C)); /* pin in AGPR quad */ \
}
#define MFMA(ACC, AF, T, C) \
  asm("v_mfma_f32_16x16x32_f16 %0, %1, %2, %0" \
      : "+v"(ACC) : "v"(AF), "a"(bf_##T##_##C));
#define COLCHAIN(ACC, C) \
  MFMA(ACC, af0, 0, C) MFMA(ACC, af1, 1, C) MFMA(ACC, af2, 2, C) MFMA(ACC, af3, 3, C)

// ---------------- Phase 2: scan (blocks 0-63) + heater (64-255) ------------
__global__ __launch_bounds__(256)
void vasicek_phase2_scan(
    const float* __restrict__ X, const float* __restrict__ r_ult,
    const float* __restrict__ mats,
    const float* __restrict__ Wp, const float* __restrict__ bp,
    const float* __restrict__ ln_g, const float* __restrict__ ln_b,
    const float* __restrict__ muW1, const float* __restrict__ mub1,
    const float* __restrict__ muW2, const float* __restrict__ mub2,
    const float* __restrict__ muW3, const float* __restrict__ mub3,
    const float* __restrict__ siW1, const float* __restrict__ sib1,
    const float* __restrict__ siW2, const float* __restrict__ sib2,
    const float* __restrict__ siW3, const float* __restrict__ sib3,
    const float* __restrict__ ws, float* __restrict__ out) {
  __shared__ __align__(16) uint16_t h1f[2][128];  // f16 h1 per MLP
  __shared__ float meanw[NSTEPS];
  __shared__ float part[256];
  __shared__ float mbuf[64];
  __shared__ float ctx_lds[192];
  __shared__ float msum[4];                        // [parity][mlp]

  const int t = threadIdx.x;

  if (blockIdx.x >= NB) {
    // DVFS heater: keep remaining CUs lightly busy until the 64 scans finish.
    float x = (float)t;
#pragma unroll 1
    for (int it = 0; it < (1 << 22); ++it) {
      if (__hip_atomic_load(&g_done, __ATOMIC_RELAXED,
                            __HIP_MEMORY_SCOPE_AGENT) >= (uint32_t)NB) break;
#pragma unroll
      for (int i = 0; i < 64; ++i) x = __builtin_fmaf(x, 1.0000001f, 1e-7f);
    }
    asm volatile("" :: "v"(x));
    return;
  }

  const int b = blockIdx.x;
  const int lane = t & 63;
  const int wv = t >> 6;

  for (int i = t; i < NSTEPS; i += 256) meanw[i] = ws[b * NSTEPS + i];

  // ---- context aggregator (all 256 threads, one T-row each) ----
  float h[64];
  {
    float x0 = X[(b * NT + t) * 2 + 0];
    float x1 = X[(b * NT + t) * 2 + 1];
    float s = 0.f;
#pragma unroll
    for (int c = 0; c < 64; ++c) {
      float pre = __builtin_fmaf(x1, Wp[64 + c], x0 * Wp[c]) + bp[c];
      h[c] = eigen_tanh(pre);
      s += h[c];
    }
    float m = s * 0.015625f;
    float vs = 0.f;
#pragma unroll
    for (int c = 0; c < 64; ++c) { float d = h[c] - m; vs = __builtin_fmaf(d, d, vs); }
    float den = sqrtf(vs * 0.015625f + 1e-5f);
#pragma unroll
    for (int c = 0; c < 64; ++c)
      h[c] = ((h[c] - m) / den) * ln_g[c] + ln_b[c];
  }
#pragma unroll
  for (int c = 0; c < 64; ++c) {
    float v = h[c];
    v += __shfl_xor(v, 32, 64); v += __shfl_xor(v, 16, 64);
    v += __shfl_xor(v, 8, 64);  v += __shfl_xor(v, 4, 64);
    v += __shfl_xor(v, 2, 64);  v += __shfl_xor(v, 1, 64);
    if (lane == 0) part[wv * 64 + c] = v;
  }
  __syncthreads();
  if (t < 64) {
    float m = ((part[t] + part[64 + t]) + (part[128 + t] + part[192 + t])) * (1.0f / 256.0f);
    mbuf[t] = m;
    ctx_lds[t] = m;
  }
  __syncthreads();
#pragma unroll
  for (int c = 0; c < 64; ++c) {
    float d = h[c] - mbuf[c];
    float v = d * d;
    v += __shfl_xor(v, 32, 64); v += __shfl_xor(v, 16, 64);
    v += __shfl_xor(v, 8, 64);  v += __shfl_xor(v, 4, 64);
    v += __shfl_xor(v, 2, 64);  v += __shfl_xor(v, 1, 64);
    if (lane == 0) part[wv * 64 + c] = v;
  }
  if (t == 255) {
#pragma unroll
    for (int c = 0; c < 64; ++c) ctx_lds[128 + c] = h[c];
  }
  __syncthreads();
  if (t < 64) {
    float vs = (part[t] + part[64 + t]) + (part[128 + t] + part[192 + t]);
    ctx_lds[64 + t] = sqrtf(vs / 255.0f);
  }
  __syncthreads();   // last whole-block barrier before wave split

  if (wv >= 2) {
    // barrier companions: match the scan loop's one barrier per step
#pragma unroll 1
    for (int s = 0; s < NSTEPS; ++s) __syncthreads();
    return;
  }

  // ---- scan waves: wave 0 = mu-MLP, wave 1 = si-MLP; lane owns j0=lane, j1=lane+64
  const int m = wv;
  const int j0 = lane, j1 = lane + 64;
  const float* W1 = m == 0 ? muW1 : siW1;
  const float* W2src = m == 0 ? muW2 : siW2;
  float c1a = (m == 0 ? mub1 : sib1)[j0];
  float c1b = (m == 0 ? mub1 : sib1)[j1];
  for (int c = 0; c < 192; ++c) {
    c1a = __builtin_fmaf(ctx_lds[c], W1[(2 + c) * 128 + j0], c1a);
    c1b = __builtin_fmaf(ctx_lds[c], W1[(2 + c) * 128 + j1], c1b);
  }
  const float w10a = W1[j0], w11a = W1[128 + j0];
  const float w10b = W1[j1], w11b = W1[128 + j1];
  const float b2a = (m == 0 ? mub2 : sib2)[j0];
  const float b2b = (m == 0 ? mub2 : sib2)[j1];
  const float w3a = (m == 0 ? muW3 : siW3)[j0];
  const float w3b = (m == 0 ? muW3 : siW3)[j1];
  const float b3mu = mub3[0];
  const float b3si = sib3[0];

  const int q = lane >> 4, n = lane & 15;

  // W2 -> 32 B-fragment quads in AGPRs (one-time; pinned)
  BDECL(0,0) BDECL(0,1) BDECL(0,2) BDECL(0,3) BDECL(0,4) BDECL(0,5) BDECL(0,6) BDECL(0,7)
  BDECL(1,0) BDECL(1,1) BDECL(1,2) BDECL(1,3) BDECL(1,4) BDECL(1,5) BDECL(1,6) BDECL(1,7)
  BDECL(2,0) BDECL(2,1) BDECL(2,2) BDECL(2,3) BDECL(2,4) BDECL(2,5) BDECL(2,6) BDECL(2,7)
  BDECL(3,0) BDECL(3,1) BDECL(3,2) BDECL(3,3) BDECL(3,4) BDECL(3,5) BDECL(3,6) BDECL(3,7)
  BINIT(0,0) BINIT(0,1) BINIT(0,2) BINIT(0,3) BINIT(0,4) BINIT(0,5) BINIT(0,6) BINIT(0,7)
  BINIT(1,0) BINIT(1,1) BINIT(1,2) BINIT(1,3) BINIT(1,4) BINIT(1,5) BINIT(1,6) BINIT(1,7)
  BINIT(2,0) BINIT(2,1) BINIT(2,2) BINIT(2,3) BINIT(2,4) BINIT(2,5) BINIT(2,6) BINIT(2,7)
  BINIT(3,0) BINIT(3,1) BINIT(3,2) BINIT(3,3) BINIT(3,4) BINIT(3,5) BINIT(3,6) BINIT(3,7)

  const u32x4* hb_ = (const u32x4*)(&h1f[m][0]);   // 16 chunks of 8 f16

  float r_mean = r_ult[b];
  float area = 0.f;

#pragma unroll 1
  for (int s = 0; s < NSTEPS; ++s) {
    f32x4 acc0 = {0.f,0.f,0.f,0.f}, acc1 = {0.f,0.f,0.f,0.f};
    f32x4 acc2 = {0.f,0.f,0.f,0.f}, acc3 = {0.f,0.f,0.f,0.f};
    f32x4 acc4 = {0.f,0.f,0.f,0.f}, acc5 = {0.f,0.f,0.f,0.f};
    f32x4 acc6 = {0.f,0.f,0.f,0.f}, acc7 = {0.f,0.f,0.f,0.f};

    const float tval = TSTEP * (float)s;
    // layer 1: lane owns (m, j0) and (m, j1)
    float ha = gelu_exact(__builtin_fmaf(tval, w11a, __builtin_fmaf(r_mean, w10a, c1a)));
    float hb = gelu_exact(__builtin_fmaf(tval, w11b, __builtin_fmaf(r_mean, w10b, c1b)));
    h1f[m][lane] = f32_to_f16bits(ha);
    h1f[m][lane + 64] = f32_to_f16bits(hb);
    // same-wave LDS write->read: in-order at the LDS unit, no barrier needed.
    // A-fragments: every lane reads its quad's chunk (rows of A all = h1).
    u32x4 af0 = hb_[q];
    u32x4 af1 = hb_[4 + q];
    u32x4 af2 = hb_[8 + q];
    u32x4 af3 = hb_[12 + q];

    // layer 2: h2 = h1 * W2 via 32 MFMA (8 col-tiles x 4-deep k-chains)
    COLCHAIN(acc0, 0) COLCHAIN(acc1, 1) COLCHAIN(acc2, 2) COLCHAIN(acc3, 3)
    COLCHAIN(acc4, 4) COLCHAIN(acc5, 5) COLCHAIN(acc6, 6) COLCHAIN(acc7, 7)
    // hazard fence: MFMA dst -> VALU read needs wait states; pass accs through
    asm volatile("s_nop 7\n\ts_nop 7"
                 : "+v"(acc0), "+v"(acc1), "+v"(acc2), "+v"(acc3),
                   "+v"(acc4), "+v"(acc5), "+v"(acc6), "+v"(acc7));

    // D rows are identical => lane's acc_c[0] = h2[16c + (lane&15)].
    const int qq = lane >> 4;
    float h2a = qq == 0 ? acc0[0] : qq == 1 ? acc1[0] : qq == 2 ? acc2[0] : acc3[0];
    float h2b = qq == 0 ? acc4[0] : qq == 1 ? acc5[0] : qq == 2 ? acc6[0] : acc7[0];
    // h2a = h2[lane], h2b = h2[lane+64]

    // layer 3: wave-internal reduce over all 128 j
    float p = __builtin_fmaf(gelu_exact(h2a + b2a), w3a,
                             gelu_exact(h2b + b2b) * w3b);
    p += __shfl_xor(p, 32, 64); p += __shfl_xor(p, 16, 64);
    p += __shfl_xor(p, 8, 64);  p += __shfl_xor(p, 4, 64);
    p += __shfl_xor(p, 2, 64);  p += __shfl_xor(p, 1, 64);
    if (lane == 0) msum[((s & 1) << 1) | m] = p;
    __syncthreads();  // the ONLY barrier per step
    const float Smu = msum[(s & 1) << 1];
    const float Ssi = msum[((s & 1) << 1) | 1];
    const float mu = Smu + b3mu;
    const float si = softplus_jax(Ssi + b3si) + 1e-5f;
    r_mean = __fadd_rn(__fadd_rn(r_mean, __fmul_rn(mu, DTF)),
                       __fmul_rn(si, meanw[s]));
    area = __fadd_rn(area, __fmul_rn(r_mean, DTF));
  }

  if (t < NMAT) {
    float mx = mats[0];
#pragma unroll
    for (int i = 1; i < NMAT; ++i) mx = fmaxf(mx, mats[i]);
    const float mm = mats[t];
    const float frac = mm / (mx + 1e-12f);
    out[b * NMAT + t] = (area * frac) / (mm + 1e-12f);
  }
  if (t == 0)
    __hip_atomic_fetch_add(&g_done, 1u, __ATOMIC_RELAXED, __HIP_MEMORY_SCOPE_AGENT);
}

extern "C" void kernel_launch(void* const* d_in, const int* in_sizes, int n_in,
                              void* d_out, int out_size, void* d_ws, size_t ws_size,
                              hipStream_t stream) {
  (void)in_sizes; (void)n_in; (void)ws_size; (void)out_size;
  const float* X      = (const float*)d_in[0];
  const float* r_ult  = (const float*)d_in[1];
  const float* mats   = (const float*)d_in[2];
  const float* Wp     = (const float*)d_in[3];
  const float* bp     = (const float*)d_in[4];
  const float* ln_g   = (const float*)d_in[5];
  const float* ln_b   = (const float*)d_in[6];
  const float* muW1   = (const float*)d_in[7];
  const float* mub1   = (const float*)d_in[8];
  const float* muW2   = (const float*)d_in[9];
  const float* mub2   = (const float*)d_in[10];
  const float* muW3   = (const float*)d_in[11];
  const float* mub3   = (const float*)d_in[12];
  const float* siW1   = (const float*)d_in[13];
  const float* sib1   = (const float*)d_in[14];
  const float* siW2   = (const float*)d_in[15];
  const float* sib2   = (const float*)d_in[16];
  const float* siW3   = (const float*)d_in[17];
  const float* sib3   = (const float*)d_in[18];
  float* ws = (float*)d_ws;   // 64*2520*4 = 645,120 bytes

  hipLaunchKernelGGL(vasicek_phase1_meandw,
                     dim3(NB * NSTEPS / 4), dim3(256), 0, stream, ws);
  hipLaunchKernelGGL(vasicek_phase2_scan,
                     dim3(256), dim3(256), 0, stream,
                     X, r_ult, mats, Wp, bp, ln_g, ln_b,
                     muW1, mub1, muW2, mub2, muW3, mub3,
                     siW1, sib1, siW2, sib2, siW3, sib3,
                     ws, (float*)d_out);
}